// Round 17
// baseline (114.710 us; speedup 1.0000x reference)
//
#include <hip/hip_runtime.h>
#include <stdint.h>

typedef float  float4v  __attribute__((ext_vector_type(4)));
typedef long long llong2v __attribute__((ext_vector_type(2)));
typedef unsigned int uint4v __attribute__((ext_vector_type(4)));

// Problem constants (N=8192, n_in=256, m=256, k=8)
// GEMM: [8192 x 512] x [512 x 8192] fp8 e4m3, fused LSTM epilogue.
// W pre-scaled by 16; acc scaled by 1/16 in epilogue.
// A  layout: [rb 64][kt 8][wm 2][j 4][gq 4][lane 16][16B]  (8KB per kt)
// Bt layout: [cb 32][kt 8][q 4][wn 4][gq 4][lane 16][16B]  (16KB per kt)
// R17: PERSISTENT blocks (grid 512 = 2/CU). Block owns rb + 4 tiles
// cb = cbg + 8t. R14's 3-slot rotation runs CONTINUOUSLY across tiles
// (g = t*8+kt, slot = g%3): next tile's kt0/kt1 stage at kt6/kt7 so the
// pipeline never drains; the epilogue runs in the free rotating slot while
// those stages are in flight. Everything L2-resident at fp8 sizes.

__device__ __forceinline__ unsigned int pk4fp8(float a, float b, float c, float d) {
  unsigned int p = (unsigned int)__builtin_amdgcn_cvt_pk_fp8_f32(a, b, 0, false);
  p = (unsigned int)__builtin_amdgcn_cvt_pk_fp8_f32(c, d, (int)p, true);
  return p;
}

__device__ __forceinline__ float sigm(float x) {
  return __builtin_amdgcn_rcpf(1.0f + __expf(-x));
}
__device__ __forceinline__ float tanh_(float x) {
  return fmaf(2.0f, __builtin_amdgcn_rcpf(1.0f + __expf(-2.0f * x)), -1.0f);
}

__device__ __forceinline__ void gll16(const void* g, void* l) {
  __builtin_amdgcn_global_load_lds((const __attribute__((address_space(1))) void*)g,
                                   (__attribute__((address_space(3))) void*)l, 16, 0, 0);
}

#define BARRIER   asm volatile("s_barrier" ::: "memory")
#define WAITLGKM  asm volatile("s_waitcnt lgkmcnt(0)" ::: "memory")
#define WAITVM(N) asm volatile("s_waitcnt vmcnt(" #N ")" ::: "memory")
#define PRIO1     __builtin_amdgcn_s_setprio(1)
#define PRIO0     __builtin_amdgcn_s_setprio(0)

// ------------- P: merged prep. blocks 0..2047 = A+logits ; 2048..3071 = Bt --------
__global__ void prep_all(const float* __restrict__ x, const float* __restrict__ h,
                         const float* __restrict__ u, const float* __restrict__ Wxz,
                         const float* __restrict__ Whz, const float* __restrict__ bxz,
                         const void* __restrict__ taup,
                         const float* __restrict__ Wx, const float* __restrict__ Wh,
                         uint8_t* __restrict__ A, uint8_t* __restrict__ Bt,
                         float* __restrict__ z_out, float* __restrict__ qz_out) {
  __shared__ float tile[64][64];

  if (blockIdx.x < 2048) {
    // ---------------- A conversion + logits ----------------
    int lane = threadIdx.x & 63;
    int n = blockIdx.x * 4 + (threadIdx.x >> 6);
    float4v xv = *(const float4v*)(x + (size_t)n * 256 + lane * 4);
    float4v hv = *(const float4v*)(h + (size_t)n * 256 + lane * 4);

    // fp8 A write: lane i covers orig k = 4i..4i+3 (x) and 256+4i.. (h)
    {
      unsigned int px = pk4fp8(xv[0], xv[1], xv[2], xv[3]);
      unsigned int ph = pk4fp8(hv[0], hv[1], hv[2], hv[3]);
      int r = n & 127;
      int gq  = (lane >> 1) & 3;
      int sub = ((lane >> 3) & 1) * 8 + (lane & 1) * 4;
      uint8_t* base = A + (size_t)(n >> 7) * 65536
                    + ((r >> 6) << 12) + (((r >> 4) & 3) << 10)
                    + (gq << 8) + ((r & 15) << 4) + sub;
      int ktx = lane >> 4;
      *(unsigned int*)(base + ktx * 8192) = px;
      *(unsigned int*)(base + (4 + ktx) * 8192) = ph;
    }

    float p[8];
#pragma unroll
    for (int j = 0; j < 8; ++j) p[j] = 0.0f;
#pragma unroll
    for (int ii = 0; ii < 4; ++ii) {
      int i = lane * 4 + ii;
      float xs = xv[ii], hs = hv[ii];
#pragma unroll
      for (int j = 0; j < 8; ++j)
        p[j] += xs * Wxz[i * 8 + j] + hs * Whz[i * 8 + j];
    }
#pragma unroll
    for (int j = 0; j < 8; ++j)
      for (int off = 32; off > 0; off >>= 1) p[j] += __shfl_down(p[j], off, 64);

    if (lane == 0) {
      int   iv = ((const int*)taup)[0];
      float fv = ((const float*)taup)[0];
      float tau = (iv >= 1 && iv < 100000) ? (float)iv : fv;
      float tinv = 1.0f / tau;

      float logit[8], e[8];
      float mx = -1e30f;
#pragma unroll
      for (int j = 0; j < 8; ++j) { logit[j] = p[j] + bxz[j]; mx = fmaxf(mx, logit[j]); }
      float s = 0.0f;
#pragma unroll
      for (int j = 0; j < 8; ++j) { e[j] = __expf(logit[j] - mx); s += e[j]; }
      float inv = 1.0f / s;
#pragma unroll
      for (int j = 0; j < 8; ++j) qz_out[(size_t)n * 8 + j] = e[j] * inv;

      float t[8];
      float mt = -1e30f;
#pragma unroll
      for (int j = 0; j < 8; ++j) {
        float uu = u[(size_t)n * 8 + j];
        float g = -__logf(-__logf(uu + 1e-10f) + 1e-10f);
        t[j] = (logit[j] + g) * tinv;
        mt = fmaxf(mt, t[j]);
      }
      float s2 = 0.0f;
#pragma unroll
      for (int j = 0; j < 8; ++j) { e[j] = __expf(t[j] - mt); s2 += e[j]; }
      float inv2 = 1.0f / s2;
#pragma unroll
      for (int j = 0; j < 8; ++j) z_out[(size_t)n * 8 + j] = e[j] * inv2;
    }
    return;
  }

  // ---------------- Bt conversion ----------------
  // p(C) = (mm>>3)*256 + (g>>1)*128 + (g&1)*64 + (kk>>1)*16 + (kk&1)*8 + (mm&7)
  int bid = blockIdx.x - 2048;
  int tid = threadIdx.x;
  int wi = bid & 7;            // 64-k window == kt
  int C0 = (bid >> 3) << 6;    // 64-col group
#pragma unroll
  for (int qq = 0; qq < 4; ++qq) {
    int flat = qq * 256 + tid;        // 1024 float4 = 64 x 64
    int rr = flat >> 4, c4 = (flat & 15) << 2;
    int ig = wi * 64 + rr;
    const float* src = (ig < 256) ? (Wx + (size_t)ig * 8192 + C0 + c4)
                                  : (Wh + (size_t)(ig - 256) * 8192 + C0 + c4);
    float4v v = *(const float4v*)src;
    float4v w;
#pragma unroll
    for (int e = 0; e < 4; ++e) w[e] = v[e] * 16.0f;
    *(float4v*)&tile[rr][c4] = w;
  }
  __syncthreads();
  int c = tid & 63, gq = tid >> 6;
  int C = C0 + c;
  int g = C >> 11, kk = (C >> 8) & 7, mm = C & 255;
  int p = ((mm >> 3) << 8) | ((g >> 1) << 7) | ((g & 1) << 6)
        | ((kk >> 1) << 4) | ((kk & 1) << 3) | (mm & 7);
  uint4v o;
  o[0] = pk4fp8(tile[gq * 8 + 0][c], tile[gq * 8 + 1][c], tile[gq * 8 + 2][c], tile[gq * 8 + 3][c]);
  o[1] = pk4fp8(tile[gq * 8 + 4][c], tile[gq * 8 + 5][c], tile[gq * 8 + 6][c], tile[gq * 8 + 7][c]);
  o[2] = pk4fp8(tile[32 + gq * 8 + 0][c], tile[32 + gq * 8 + 1][c], tile[32 + gq * 8 + 2][c], tile[32 + gq * 8 + 3][c]);
  o[3] = pk4fp8(tile[32 + gq * 8 + 4][c], tile[32 + gq * 8 + 5][c], tile[32 + gq * 8 + 6][c], tile[32 + gq * 8 + 7][c]);
  int cl = p & 255;   // q=cl>>6, wn=(cl>>4)&3, lane=cl&15
  int off = ((cl >> 6) << 12) + (((cl >> 4) & 3) << 10) + (gq << 8) + ((cl & 15) << 4);
  *(uint4v*)(Bt + (size_t)(p >> 8) * 131072 + wi * 16384 + off) = o;
}

// ---------------- G: persistent fp8 128x256-tile GEMM, continuous rotation -------
// Grid 512 (2/CU). Block: fixed rb, tiles t=0..3 with cb = cbg + 8t.
// 8 waves = 2M(wm) x 4N(wn). Per wave: 64 rows (wm*64 + j*16 + gl*4 + r),
// lane cols = 4 gate-quadrants q of one (kk,mm): kk = wn*2+(ml>>3), mml = ml&7.
__global__ __launch_bounds__(512, 4) void gates_kernel(
    const uint8_t* __restrict__ A,    // [rb 64][kt 8][8KB] fp8
    const uint8_t* __restrict__ Bt,   // [cb 32][kt 8][16KB] fp8
    const float* __restrict__ c0g,    // [8192][256]
    const float* __restrict__ bias,   // [8192]
    const float* __restrict__ zg,     // [8192][8]
    float* __restrict__ h_out, float* __restrict__ c_out) {
  __shared__ char smem[73728];  // 3 slots x 24KB (A 8KB + B 16KB per slot)

  const int tid = threadIdx.x;
  const int lane = tid & 63, ml = lane & 15, gl = lane >> 4;
  const int wid = tid >> 6, wm = wid >> 2, wn = wid & 3;

  // XCD-stripe: xcd owns rb {8x..8x+7}; per XCD: 8 rb x 8 cbg.
  const int xcd = blockIdx.x & 7;
  const int j_  = blockIdx.x >> 3;          // 0..63
  const int rb  = (xcd << 3) | (j_ & 7);    // 0..63
  const int cbg = j_ >> 3;                  // 0..7
  const int row0 = rb << 7;

  const uint8_t* Abp = A + (size_t)rb * 65536;

  // fragment LDS bases — quarter-wave-contiguous (conflict-free, R9-verified)
  const char* pa = smem + (wm << 12) + (gl << 8) + (ml << 4);           // + slot*24576 + j*1024
  const char* pb = smem + 8192 + (wn << 10) + (gl << 8) + (ml << 4);    // + slot*24576 + q*4096

#define STGF(BBP, KTS, SL) do { \
    gll16(Abp + (KTS) * 8192 + (tid << 4), smem + (SL) * 24576 + (tid << 4)); \
    gll16((BBP) + (KTS) * 16384 + (tid << 4), smem + (SL) * 24576 + 8192 + (tid << 4)); \
    gll16((BBP) + (KTS) * 16384 + 8192 + (tid << 4), smem + (SL) * 24576 + 16384 + (tid << 4)); \
  } while (0)

#define RDAB(SL) { \
    _Pragma("unroll") for (int j = 0; j < 4; ++j) \
      af[j] = *(const llong2v*)(pa + (SL) * 24576 + j * 1024); \
    _Pragma("unroll") for (int q = 0; q < 4; ++q) \
      bf[q] = *(const llong2v*)(pb + (SL) * 24576 + q * 4096); }

#define MMALL() { _Pragma("unroll") for (int j = 0; j < 4; ++j) \
    _Pragma("unroll") for (int q = 0; q < 4; ++q) { \
      acc[q][j] = __builtin_amdgcn_mfma_f32_16x16x32_fp8_fp8(af[j][0], bf[q][0], acc[q][j], 0, 0, 0); \
      acc[q][j] = __builtin_amdgcn_mfma_f32_16x16x32_fp8_fp8(af[j][1], bf[q][1], acc[q][j], 0, 0, 0); } }

  float4v acc[4][4];   // [gate q][row frag j]
  llong2v af[4], bf[4];

  const int kkl = (wn << 1) | (ml >> 3);
  const int mml = ml & 7;
  const float s16 = 0.0625f;   // undo W*16 pre-scale

  int sl_read = 0, sl_stage = 2;

  // prologue: stage g=0 (slot 0) and g=1 (slot 1)
  {
    const uint8_t* Bb0 = Bt + (size_t)cbg * 131072;
    STGF(Bb0, 0, 0);
    STGF(Bb0, 1, 1);
  }
  WAITVM(3);
  BARRIER;

  for (int t = 0; t < 4; ++t) {
    const int cb = cbg + 8 * t;
    const uint8_t* Bb_c = Bt + (size_t)cb * 131072;
    const uint8_t* Bb_n = Bt + (size_t)(cb + 8 >= 32 ? cb : cb + 8) * 131072;

#pragma unroll
    for (int q = 0; q < 4; ++q)
#pragma unroll
      for (int j = 0; j < 4; ++j)
#pragma unroll
        for (int r = 0; r < 4; ++r) acc[q][j][r] = 0.0f;

#pragma unroll
    for (int kt = 0; kt < 8; ++kt) {
      if (kt < 6) {
        STGF(Bb_c, kt + 2, sl_stage);
        WAITVM(3);
      } else if (t < 3) {
        STGF(Bb_n, (kt + 2) & 7, sl_stage);   // next tile's kt0/kt1
        WAITVM(3);
      } else if (kt == 6) {
        WAITVM(0);                             // final drain (last tile)
      }
      RDAB(sl_read);
      PRIO1; MMALL(); PRIO0;       // 32 MFMA
      BARRIER;
      sl_read  = (sl_read  == 2) ? 0 : sl_read + 1;
      sl_stage = (sl_stage == 2) ? 0 : sl_stage + 1;
    }

    // ------------- epilogue for tile t (pbuf in the free rotating slot) ---------
    {
      const int pbuf_sl = (2 * t + 1) % 3;     // == (8t+7)%3, distinct from in-flight slots
      float* pbuf = (float*)(smem + pbuf_sl * 24576);   // [wn 4][row 128][8] = 16KB
      const int mmg = (cb << 3) + mml;
      const float bI = bias[0 * 2048 + kkl * 256 + mmg];
      const float bG = bias[1 * 2048 + kkl * 256 + mmg];
      const float bF = bias[2 * 2048 + kkl * 256 + mmg];
      const float bO = bias[3 * 2048 + kkl * 256 + mmg];

      float hpart[4][4], cpart[4][4];
#pragma unroll
      for (int j = 0; j < 4; ++j) {
        const int nb = row0 + (wm << 6) + (j << 4) + (gl << 2);
#pragma unroll
        for (int r = 0; r < 4; ++r) {
          const int nrow = nb + r;
          float I = fmaf(acc[0][j][r], s16, bI);
          float G = fmaf(acc[1][j][r], s16, bG);
          float F = fmaf(acc[2][j][r], s16, bF);
          float O = fmaf(acc[3][j][r], s16, bO);
          float c0v = c0g[(size_t)nrow * 256 + mmg];
          float ct = fmaf(sigm(F), c0v, sigm(I) * tanh_(G));
          float ht = sigm(O) * tanh_(ct);
          float zv = zg[(size_t)nrow * 8 + kkl];
          float h1 = zv * ht, c1 = zv * ct;
          h1 += __shfl_xor(h1, 8, 64);    // combine the wave's kk pair
          c1 += __shfl_xor(c1, 8, 64);
          hpart[j][r] = h1;
          cpart[j][r] = c1;
        }
      }

      const bool wr = ((ml & 8) == 0);
      // ---- pass 1: h
      if (wr) {
#pragma unroll
        for (int j = 0; j < 4; ++j)
#pragma unroll
          for (int r = 0; r < 4; ++r) {
            int rloc = (wm << 6) + (j << 4) + (gl << 2) + r;
            pbuf[(wn << 10) + (rloc << 3) + mml] = hpart[j][r];
          }
      }
      WAITLGKM; BARRIER;
#pragma unroll
      for (int i = 0; i < 2; ++i) {
        int idx = (i << 9) + tid;          // 0..1023 = 128 rows x 8 cols
        int rloc = idx >> 3, mm2 = idx & 7;
        float v = pbuf[(rloc << 3) + mm2] + pbuf[1024 + (rloc << 3) + mm2]
                + pbuf[2048 + (rloc << 3) + mm2] + pbuf[3072 + (rloc << 3) + mm2];
        h_out[(size_t)(row0 + rloc) * 256 + (cb << 3) + mm2] = v;
      }
      WAITLGKM; BARRIER;
      // ---- pass 2: c
      if (wr) {
#pragma unroll
        for (int j = 0; j < 4; ++j)
#pragma unroll
          for (int r = 0; r < 4; ++r) {
            int rloc = (wm << 6) + (j << 4) + (gl << 2) + r;
            pbuf[(wn << 10) + (rloc << 3) + mml] = cpart[j][r];
          }
      }
      WAITLGKM; BARRIER;
#pragma unroll
      for (int i = 0; i < 2; ++i) {
        int idx = (i << 9) + tid;
        int rloc = idx >> 3, mm2 = idx & 7;
        float v = pbuf[(rloc << 3) + mm2] + pbuf[1024 + (rloc << 3) + mm2]
                + pbuf[2048 + (rloc << 3) + mm2] + pbuf[3072 + (rloc << 3) + mm2];
        c_out[(size_t)(row0 + rloc) * 256 + (cb << 3) + mm2] = v;
      }
      WAITLGKM; BARRIER;   // pbuf reads done before next tile overwrites this slot
    }
  }
#undef STGF
#undef RDAB
#undef MMALL
}

extern "C" void kernel_launch(void* const* d_in, const int* in_sizes, int n_in,
                              void* d_out, int out_size, void* d_ws, size_t ws_size,
                              hipStream_t stream) {
  const float* x   = (const float*)d_in[0];
  const float* h0  = (const float*)d_in[1];
  const float* c0  = (const float*)d_in[2];
  const float* u   = (const float*)d_in[3];
  const float* Wxz = (const float*)d_in[4];
  const float* Whz = (const float*)d_in[5];
  const float* Wx4 = (const float*)d_in[6];
  const float* Wh4 = (const float*)d_in[7];
  const float* bxz = (const float*)d_in[8];
  const float* b4  = (const float*)d_in[9];
  const void*  tau = d_in[10];

  float* out    = (float*)d_out;
  float* z_out  = out;                       // [8192][8]
  float* qz_out = out + 65536;               // [8192][8]
  float* h_out  = out + 131072;              // [8192][256]
  float* c_out  = out + 131072 + 2097152;    // [8192][256]

  uint8_t* A  = (uint8_t*)d_ws;              // 4MB fp8
  uint8_t* Bt = A + 4194304;                 // 4MB fp8

  prep_all<<<3072, 256, 0, stream>>>(x, h0, u, Wxz, Whz, bxz, tau,
                                     Wx4, Wh4, A, Bt, z_out, qz_out);
  gates_kernel<<<512, 512, 0, stream>>>(A, Bt, c0, b4, z_out, h_out, c_out);
}

// Round 18
// 113.795 us; speedup vs baseline: 1.0080x; 1.0080x over previous
//
#include <hip/hip_runtime.h>
#include <stdint.h>

typedef float  float4v  __attribute__((ext_vector_type(4)));
typedef long long llong2v __attribute__((ext_vector_type(2)));
typedef unsigned int uint4v __attribute__((ext_vector_type(4)));

// Problem constants (N=8192, n_in=256, m=256, k=8)
// GEMM: [8192 x 512] x [512 x 8192] fp8 e4m3, fused LSTM epilogue.
// W pre-scaled by 16; acc scaled by 1/16 in epilogue.
// A  layout: [rb 64][kt 8][wm 2][j 4][gq 4][lane 16][16B]  (8KB per kt)
// Bt layout: [cb 32][kt 8][q 4][wn 4][gq 4][lane 16][16B]  (16KB per kt)
// R18 = R14 (best verified: 3-slot rotation, one barrier/kt, counted vmcnt)
// + epilogue-operand prefetch at kt==6 (c0/zg/bias gathers hide under the
// last two MFMA clusters; WAITVM(36) keeps the staging ledger intact).

__device__ __forceinline__ unsigned int pk4fp8(float a, float b, float c, float d) {
  unsigned int p = (unsigned int)__builtin_amdgcn_cvt_pk_fp8_f32(a, b, 0, false);
  p = (unsigned int)__builtin_amdgcn_cvt_pk_fp8_f32(c, d, (int)p, true);
  return p;
}

__device__ __forceinline__ float sigm(float x) {
  return __builtin_amdgcn_rcpf(1.0f + __expf(-x));
}
__device__ __forceinline__ float tanh_(float x) {
  return fmaf(2.0f, __builtin_amdgcn_rcpf(1.0f + __expf(-2.0f * x)), -1.0f);
}

__device__ __forceinline__ void gll16(const void* g, void* l) {
  __builtin_amdgcn_global_load_lds((const __attribute__((address_space(1))) void*)g,
                                   (__attribute__((address_space(3))) void*)l, 16, 0, 0);
}

#define BARRIER   asm volatile("s_barrier" ::: "memory")
#define WAITLGKM  asm volatile("s_waitcnt lgkmcnt(0)" ::: "memory")
#define WAITVM(N) asm volatile("s_waitcnt vmcnt(" #N ")" ::: "memory")
#define PRIO1     __builtin_amdgcn_s_setprio(1)
#define PRIO0     __builtin_amdgcn_s_setprio(0)

// ------------- P: merged prep. blocks 0..2047 = A+logits ; 2048..3071 = Bt --------
__global__ void prep_all(const float* __restrict__ x, const float* __restrict__ h,
                         const float* __restrict__ u, const float* __restrict__ Wxz,
                         const float* __restrict__ Whz, const float* __restrict__ bxz,
                         const void* __restrict__ taup,
                         const float* __restrict__ Wx, const float* __restrict__ Wh,
                         uint8_t* __restrict__ A, uint8_t* __restrict__ Bt,
                         float* __restrict__ z_out, float* __restrict__ qz_out) {
  __shared__ float tile[64][64];

  if (blockIdx.x < 2048) {
    // ---------------- A conversion + logits ----------------
    int lane = threadIdx.x & 63;
    int n = blockIdx.x * 4 + (threadIdx.x >> 6);
    float4v xv = *(const float4v*)(x + (size_t)n * 256 + lane * 4);
    float4v hv = *(const float4v*)(h + (size_t)n * 256 + lane * 4);

    // fp8 A write: lane i covers orig k = 4i..4i+3 (x) and 256+4i.. (h)
    {
      unsigned int px = pk4fp8(xv[0], xv[1], xv[2], xv[3]);
      unsigned int ph = pk4fp8(hv[0], hv[1], hv[2], hv[3]);
      int r = n & 127;
      int gq  = (lane >> 1) & 3;
      int sub = ((lane >> 3) & 1) * 8 + (lane & 1) * 4;
      uint8_t* base = A + (size_t)(n >> 7) * 65536
                    + ((r >> 6) << 12) + (((r >> 4) & 3) << 10)
                    + (gq << 8) + ((r & 15) << 4) + sub;
      int ktx = lane >> 4;
      *(unsigned int*)(base + ktx * 8192) = px;
      *(unsigned int*)(base + (4 + ktx) * 8192) = ph;
    }

    float p[8];
#pragma unroll
    for (int j = 0; j < 8; ++j) p[j] = 0.0f;
#pragma unroll
    for (int ii = 0; ii < 4; ++ii) {
      int i = lane * 4 + ii;
      float xs = xv[ii], hs = hv[ii];
#pragma unroll
      for (int j = 0; j < 8; ++j)
        p[j] += xs * Wxz[i * 8 + j] + hs * Whz[i * 8 + j];
    }
#pragma unroll
    for (int j = 0; j < 8; ++j)
      for (int off = 32; off > 0; off >>= 1) p[j] += __shfl_down(p[j], off, 64);

    if (lane == 0) {
      int   iv = ((const int*)taup)[0];
      float fv = ((const float*)taup)[0];
      float tau = (iv >= 1 && iv < 100000) ? (float)iv : fv;
      float tinv = 1.0f / tau;

      float logit[8], e[8];
      float mx = -1e30f;
#pragma unroll
      for (int j = 0; j < 8; ++j) { logit[j] = p[j] + bxz[j]; mx = fmaxf(mx, logit[j]); }
      float s = 0.0f;
#pragma unroll
      for (int j = 0; j < 8; ++j) { e[j] = __expf(logit[j] - mx); s += e[j]; }
      float inv = 1.0f / s;
#pragma unroll
      for (int j = 0; j < 8; ++j) qz_out[(size_t)n * 8 + j] = e[j] * inv;

      float t[8];
      float mt = -1e30f;
#pragma unroll
      for (int j = 0; j < 8; ++j) {
        float uu = u[(size_t)n * 8 + j];
        float g = -__logf(-__logf(uu + 1e-10f) + 1e-10f);
        t[j] = (logit[j] + g) * tinv;
        mt = fmaxf(mt, t[j]);
      }
      float s2 = 0.0f;
#pragma unroll
      for (int j = 0; j < 8; ++j) { e[j] = __expf(t[j] - mt); s2 += e[j]; }
      float inv2 = 1.0f / s2;
#pragma unroll
      for (int j = 0; j < 8; ++j) z_out[(size_t)n * 8 + j] = e[j] * inv2;
    }
    return;
  }

  // ---------------- Bt conversion ----------------
  // p(C) = (mm>>3)*256 + (g>>1)*128 + (g&1)*64 + (kk>>1)*16 + (kk&1)*8 + (mm&7)
  int bid = blockIdx.x - 2048;
  int tid = threadIdx.x;
  int wi = bid & 7;            // 64-k window == kt
  int C0 = (bid >> 3) << 6;    // 64-col group
#pragma unroll
  for (int qq = 0; qq < 4; ++qq) {
    int flat = qq * 256 + tid;        // 1024 float4 = 64 x 64
    int rr = flat >> 4, c4 = (flat & 15) << 2;
    int ig = wi * 64 + rr;
    const float* src = (ig < 256) ? (Wx + (size_t)ig * 8192 + C0 + c4)
                                  : (Wh + (size_t)(ig - 256) * 8192 + C0 + c4);
    float4v v = *(const float4v*)src;
    float4v w;
#pragma unroll
    for (int e = 0; e < 4; ++e) w[e] = v[e] * 16.0f;
    *(float4v*)&tile[rr][c4] = w;
  }
  __syncthreads();
  int c = tid & 63, gq = tid >> 6;
  int C = C0 + c;
  int g = C >> 11, kk = (C >> 8) & 7, mm = C & 255;
  int p = ((mm >> 3) << 8) | ((g >> 1) << 7) | ((g & 1) << 6)
        | ((kk >> 1) << 4) | ((kk & 1) << 3) | (mm & 7);
  uint4v o;
  o[0] = pk4fp8(tile[gq * 8 + 0][c], tile[gq * 8 + 1][c], tile[gq * 8 + 2][c], tile[gq * 8 + 3][c]);
  o[1] = pk4fp8(tile[gq * 8 + 4][c], tile[gq * 8 + 5][c], tile[gq * 8 + 6][c], tile[gq * 8 + 7][c]);
  o[2] = pk4fp8(tile[32 + gq * 8 + 0][c], tile[32 + gq * 8 + 1][c], tile[32 + gq * 8 + 2][c], tile[32 + gq * 8 + 3][c]);
  o[3] = pk4fp8(tile[32 + gq * 8 + 4][c], tile[32 + gq * 8 + 5][c], tile[32 + gq * 8 + 6][c], tile[32 + gq * 8 + 7][c]);
  int cl = p & 255;   // q=cl>>6, wn=(cl>>4)&3, lane=cl&15
  int off = ((cl >> 6) << 12) + (((cl >> 4) & 3) << 10) + (gq << 8) + ((cl & 15) << 4);
  *(uint4v*)(Bt + (size_t)(p >> 8) * 131072 + wi * 16384 + off) = o;
}

// ---------------- G: fp8 128x256-tile GEMM, 3-slot rotation -----------------------
// 8 waves = 2M(wm) x 4N(wn). Per wave: 64 rows (wm*64 + j*16 + gl*4 + r),
// lane cols = 4 gate-quadrants q of one (kk,mm): kk = wn*2+(ml>>3), mml = ml&7.
// acc[q][j]: 16 float4v = 64 f32/lane.
__global__ __launch_bounds__(512, 4) void gates_kernel(
    const uint8_t* __restrict__ A,    // [rb 64][kt 8][8KB] fp8
    const uint8_t* __restrict__ Bt,   // [cb 32][kt 8][16KB] fp8
    const float* __restrict__ c0g,    // [8192][256]
    const float* __restrict__ bias,   // [8192]
    const float* __restrict__ zg,     // [8192][8]
    float* __restrict__ h_out, float* __restrict__ c_out) {
  __shared__ char smem[73728];  // 3 slots x 24KB (A 8KB + B 16KB per slot)

  const int tid = threadIdx.x;
  const int lane = tid & 63, ml = lane & 15, gl = lane >> 4;
  const int wid = tid >> 6, wm = wid >> 2, wn = wid & 3;

  // XCD-stripe: xcd owns rb {8x..8x+7}, cb outer / rb inner.
  const int xcd = blockIdx.x & 7;
  const int j_  = blockIdx.x >> 3;          // 0..255
  const int cb  = j_ >> 3;                  // 0..31
  const int rb  = (xcd << 3) | (j_ & 7);    // 0..63
  const int row0 = rb << 7;

  const uint8_t* Abp = A + (size_t)rb * 65536;
  const uint8_t* Bbp = Bt + (size_t)cb * 131072;

  // fragment LDS bases — quarter-wave-contiguous (conflict-free, R9-verified)
  const char* pa = smem + (wm << 12) + (gl << 8) + (ml << 4);           // + slot*24576 + j*1024
  const char* pb = smem + 8192 + (wn << 10) + (gl << 8) + (ml << 4);    // + slot*24576 + q*4096

  // epilogue lane constants (hoisted for the kt==6 prefetch)
  const int kkl = (wn << 1) | (ml >> 3);
  const int mml = ml & 7;
  const int mmg = (cb << 3) + mml;

  // stage kt-slot: A 8KB + B 16KB = 3 gll16/thread, fully linear
#define STGF(KTS) do { \
    const int sl_ = (KTS) % 3; \
    gll16(Abp + ((KTS) & 7) * 8192 + (tid << 4), \
          smem + sl_ * 24576 + (tid << 4)); \
    _Pragma("unroll") for (int s_ = 0; s_ < 2; ++s_) \
      gll16(Bbp + ((KTS) & 7) * 16384 + s_ * 8192 + (tid << 4), \
            smem + sl_ * 24576 + 8192 + s_ * 8192 + (tid << 4)); \
  } while (0)

#define RDAB(SL) { \
    _Pragma("unroll") for (int j = 0; j < 4; ++j) \
      af[j] = *(const llong2v*)(pa + (SL) * 24576 + j * 1024); \
    _Pragma("unroll") for (int q = 0; q < 4; ++q) \
      bf[q] = *(const llong2v*)(pb + (SL) * 24576 + q * 4096); }

#define MMALL() { _Pragma("unroll") for (int j = 0; j < 4; ++j) \
    _Pragma("unroll") for (int q = 0; q < 4; ++q) { \
      acc[q][j] = __builtin_amdgcn_mfma_f32_16x16x32_fp8_fp8(af[j][0], bf[q][0], acc[q][j], 0, 0, 0); \
      acc[q][j] = __builtin_amdgcn_mfma_f32_16x16x32_fp8_fp8(af[j][1], bf[q][1], acc[q][j], 0, 0, 0); } }

  float4v acc[4][4];   // [gate q][row frag j]
#pragma unroll
  for (int q = 0; q < 4; ++q)
#pragma unroll
    for (int j = 0; j < 4; ++j)
#pragma unroll
      for (int r = 0; r < 4; ++r) acc[q][j][r] = 0.0f;

  llong2v af[4], bf[4];
  float c0v[4][4], zv[4][4];
  float bI, bG, bF, bO;

  // prologue: stage kt0,kt1 (6 loads); own s0 landed at vmcnt(3); barrier = all
  STGF(0); STGF(1);
  WAITVM(3);
  BARRIER;

#pragma unroll
  for (int kt = 0; kt < 8; ++kt) {
    if (kt <= 5) {
      STGF(kt + 2);                // slot (kt+2)%3 = (kt-1)%3: readers done pre-BARRIER_{kt-1}
      WAITVM(3);                   // leave only s(kt+2): s(kt+1) landed before BARRIER_kt
    } else if (kt == 6) {
      // prefetch epilogue gathers (36 loads) — latency hides under the last
      // two MFMA clusters; WAITVM(36) still drains s7's 3 older stages.
#pragma unroll
      for (int j = 0; j < 4; ++j)
#pragma unroll
        for (int r = 0; r < 4; ++r) {
          int nrow = row0 + (wm << 6) + (j << 4) + (gl << 2) + r;
          c0v[j][r] = c0g[(size_t)nrow * 256 + mmg];
          zv[j][r]  = zg[(size_t)nrow * 8 + kkl];
        }
      bI = bias[0 * 2048 + kkl * 256 + mmg];
      bG = bias[1 * 2048 + kkl * 256 + mmg];
      bF = bias[2 * 2048 + kkl * 256 + mmg];
      bO = bias[3 * 2048 + kkl * 256 + mmg];
      WAITVM(36);
    }
    RDAB(kt % 3);                  // 8 x ds_read_b128 (compiler emits counted lgkm waits)
    PRIO1; MMALL(); PRIO0;         // 32 MFMA — overlaps the in-flight stage
    BARRIER;                       // single barrier per kt
  }
#undef STGF
#undef RDAB
#undef MMALL

  // ---------------- fused LSTM epilogue (all slots free after BARRIER_7) ----------
  {
    const float s16 = 0.0625f;   // undo W*16 pre-scale

    float hpart[4][4], cpart[4][4];
#pragma unroll
    for (int j = 0; j < 4; ++j) {
#pragma unroll
      for (int r = 0; r < 4; ++r) {
        float I = fmaf(acc[0][j][r], s16, bI);
        float G = fmaf(acc[1][j][r], s16, bG);
        float F = fmaf(acc[2][j][r], s16, bF);
        float O = fmaf(acc[3][j][r], s16, bO);
        float ct = fmaf(sigm(F), c0v[j][r], sigm(I) * tanh_(G));
        float ht = sigm(O) * tanh_(ct);
        float h1 = zv[j][r] * ht, c1 = zv[j][r] * ct;
        h1 += __shfl_xor(h1, 8, 64);    // combine the wave's kk pair
        c1 += __shfl_xor(c1, 8, 64);
        hpart[j][r] = h1;
        cpart[j][r] = c1;
      }
    }

    // pbuf [wn 4][row 128][16] : cols 0..7 = h, 8..15 = c (32KB, reuses slots 0-1)
    float* pbuf = (float*)smem;
    const bool wr = ((ml & 8) == 0);
    if (wr) {
#pragma unroll
      for (int j = 0; j < 4; ++j)
#pragma unroll
        for (int r = 0; r < 4; ++r) {
          int rloc = (wm << 6) + (j << 4) + (gl << 2) + r;
          pbuf[(wn << 11) + (rloc << 4) + mml]     = hpart[j][r];
          pbuf[(wn << 11) + (rloc << 4) + 8 + mml] = cpart[j][r];
        }
    }
    WAITLGKM; BARRIER;
    // reduce over wn and store: 128 rows x 8 cols, h+c, 2 idx/thread
#pragma unroll
    for (int i = 0; i < 2; ++i) {
      int idx = (i << 9) + tid;          // 0..1023
      int rloc = idx >> 3, mm2 = idx & 7;
      float hv = pbuf[(rloc << 4) + mm2]
               + pbuf[2048 + (rloc << 4) + mm2]
               + pbuf[4096 + (rloc << 4) + mm2]
               + pbuf[6144 + (rloc << 4) + mm2];
      float cv = pbuf[(rloc << 4) + 8 + mm2]
               + pbuf[2048 + (rloc << 4) + 8 + mm2]
               + pbuf[4096 + (rloc << 4) + 8 + mm2]
               + pbuf[6144 + (rloc << 4) + 8 + mm2];
      h_out[(size_t)(row0 + rloc) * 256 + (cb << 3) + mm2] = hv;
      c_out[(size_t)(row0 + rloc) * 256 + (cb << 3) + mm2] = cv;
    }
  }
}

extern "C" void kernel_launch(void* const* d_in, const int* in_sizes, int n_in,
                              void* d_out, int out_size, void* d_ws, size_t ws_size,
                              hipStream_t stream) {
  const float* x   = (const float*)d_in[0];
  const float* h0  = (const float*)d_in[1];
  const float* c0  = (const float*)d_in[2];
  const float* u   = (const float*)d_in[3];
  const float* Wxz = (const float*)d_in[4];
  const float* Whz = (const float*)d_in[5];
  const float* Wx4 = (const float*)d_in[6];
  const float* Wh4 = (const float*)d_in[7];
  const float* bxz = (const float*)d_in[8];
  const float* b4  = (const float*)d_in[9];
  const void*  tau = d_in[10];

  float* out    = (float*)d_out;
  float* z_out  = out;                       // [8192][8]
  float* qz_out = out + 65536;               // [8192][8]
  float* h_out  = out + 131072;              // [8192][256]
  float* c_out  = out + 131072 + 2097152;    // [8192][256]

  uint8_t* A  = (uint8_t*)d_ws;              // 4MB fp8
  uint8_t* Bt = A + 4194304;                 // 4MB fp8

  prep_all<<<3072, 256, 0, stream>>>(x, h0, u, Wxz, Whz, bxz, tau,
                                     Wx4, Wh4, A, Bt, z_out, qz_out);
  gates_kernel<<<2048, 512, 0, stream>>>(A, Bt, c0, b4, z_out, h_out, c_out);
}

// Round 19
// 80.728 us; speedup vs baseline: 1.4209x; 1.4096x over previous
//
#include <hip/hip_runtime.h>
#include <stdint.h>

typedef float  float4v  __attribute__((ext_vector_type(4)));
typedef long long llong2v __attribute__((ext_vector_type(2)));
typedef unsigned int uint4v __attribute__((ext_vector_type(4)));

// Problem constants (N=8192, n_in=256, m=256, k=8)
// GEMM: [8192 x 512] x [512 x 8192] fp8 e4m3, fused LSTM epilogue.
// W pre-scaled by 16; acc scaled by 1/16 in epilogue.
// A  layout: [rb 64][kt 8][wm 2][j 4][gq 4][lane 16][16B]  (8KB per kt)
// Bt layout: [cb 32][kt 8][q 4][wn 4][gq 4][lane 16][16B]  (16KB per kt)
// R19 = exact revert to R14 (best verified: 3-slot LDS rotation, one barrier
// per kt, counted vmcnt(3), no cross-loop epilogue prefetch — R18 showed that
// extra live state spills at this register footprint).

__device__ __forceinline__ unsigned int pk4fp8(float a, float b, float c, float d) {
  unsigned int p = (unsigned int)__builtin_amdgcn_cvt_pk_fp8_f32(a, b, 0, false);
  p = (unsigned int)__builtin_amdgcn_cvt_pk_fp8_f32(c, d, (int)p, true);
  return p;
}

__device__ __forceinline__ float sigm(float x) {
  return __builtin_amdgcn_rcpf(1.0f + __expf(-x));
}
__device__ __forceinline__ float tanh_(float x) {
  return fmaf(2.0f, __builtin_amdgcn_rcpf(1.0f + __expf(-2.0f * x)), -1.0f);
}

__device__ __forceinline__ void gll16(const void* g, void* l) {
  __builtin_amdgcn_global_load_lds((const __attribute__((address_space(1))) void*)g,
                                   (__attribute__((address_space(3))) void*)l, 16, 0, 0);
}

#define BARRIER   asm volatile("s_barrier" ::: "memory")
#define WAITLGKM  asm volatile("s_waitcnt lgkmcnt(0)" ::: "memory")
#define WAITVM(N) asm volatile("s_waitcnt vmcnt(" #N ")" ::: "memory")
#define PRIO1     __builtin_amdgcn_s_setprio(1)
#define PRIO0     __builtin_amdgcn_s_setprio(0)

// ------------- P: merged prep. blocks 0..2047 = A+logits ; 2048..3071 = Bt --------
__global__ void prep_all(const float* __restrict__ x, const float* __restrict__ h,
                         const float* __restrict__ u, const float* __restrict__ Wxz,
                         const float* __restrict__ Whz, const float* __restrict__ bxz,
                         const void* __restrict__ taup,
                         const float* __restrict__ Wx, const float* __restrict__ Wh,
                         uint8_t* __restrict__ A, uint8_t* __restrict__ Bt,
                         float* __restrict__ z_out, float* __restrict__ qz_out) {
  __shared__ float tile[64][64];

  if (blockIdx.x < 2048) {
    // ---------------- A conversion + logits ----------------
    int lane = threadIdx.x & 63;
    int n = blockIdx.x * 4 + (threadIdx.x >> 6);
    float4v xv = *(const float4v*)(x + (size_t)n * 256 + lane * 4);
    float4v hv = *(const float4v*)(h + (size_t)n * 256 + lane * 4);

    // fp8 A write: lane i covers orig k = 4i..4i+3 (x) and 256+4i.. (h)
    {
      unsigned int px = pk4fp8(xv[0], xv[1], xv[2], xv[3]);
      unsigned int ph = pk4fp8(hv[0], hv[1], hv[2], hv[3]);
      int r = n & 127;
      int gq  = (lane >> 1) & 3;
      int sub = ((lane >> 3) & 1) * 8 + (lane & 1) * 4;
      uint8_t* base = A + (size_t)(n >> 7) * 65536
                    + ((r >> 6) << 12) + (((r >> 4) & 3) << 10)
                    + (gq << 8) + ((r & 15) << 4) + sub;
      int ktx = lane >> 4;
      *(unsigned int*)(base + ktx * 8192) = px;
      *(unsigned int*)(base + (4 + ktx) * 8192) = ph;
    }

    float p[8];
#pragma unroll
    for (int j = 0; j < 8; ++j) p[j] = 0.0f;
#pragma unroll
    for (int ii = 0; ii < 4; ++ii) {
      int i = lane * 4 + ii;
      float xs = xv[ii], hs = hv[ii];
#pragma unroll
      for (int j = 0; j < 8; ++j)
        p[j] += xs * Wxz[i * 8 + j] + hs * Whz[i * 8 + j];
    }
#pragma unroll
    for (int j = 0; j < 8; ++j)
      for (int off = 32; off > 0; off >>= 1) p[j] += __shfl_down(p[j], off, 64);

    if (lane == 0) {
      int   iv = ((const int*)taup)[0];
      float fv = ((const float*)taup)[0];
      float tau = (iv >= 1 && iv < 100000) ? (float)iv : fv;
      float tinv = 1.0f / tau;

      float logit[8], e[8];
      float mx = -1e30f;
#pragma unroll
      for (int j = 0; j < 8; ++j) { logit[j] = p[j] + bxz[j]; mx = fmaxf(mx, logit[j]); }
      float s = 0.0f;
#pragma unroll
      for (int j = 0; j < 8; ++j) { e[j] = __expf(logit[j] - mx); s += e[j]; }
      float inv = 1.0f / s;
#pragma unroll
      for (int j = 0; j < 8; ++j) qz_out[(size_t)n * 8 + j] = e[j] * inv;

      float t[8];
      float mt = -1e30f;
#pragma unroll
      for (int j = 0; j < 8; ++j) {
        float uu = u[(size_t)n * 8 + j];
        float g = -__logf(-__logf(uu + 1e-10f) + 1e-10f);
        t[j] = (logit[j] + g) * tinv;
        mt = fmaxf(mt, t[j]);
      }
      float s2 = 0.0f;
#pragma unroll
      for (int j = 0; j < 8; ++j) { e[j] = __expf(t[j] - mt); s2 += e[j]; }
      float inv2 = 1.0f / s2;
#pragma unroll
      for (int j = 0; j < 8; ++j) z_out[(size_t)n * 8 + j] = e[j] * inv2;
    }
    return;
  }

  // ---------------- Bt conversion ----------------
  // p(C) = (mm>>3)*256 + (g>>1)*128 + (g&1)*64 + (kk>>1)*16 + (kk&1)*8 + (mm&7)
  int bid = blockIdx.x - 2048;
  int tid = threadIdx.x;
  int wi = bid & 7;            // 64-k window == kt
  int C0 = (bid >> 3) << 6;    // 64-col group
#pragma unroll
  for (int qq = 0; qq < 4; ++qq) {
    int flat = qq * 256 + tid;        // 1024 float4 = 64 x 64
    int rr = flat >> 4, c4 = (flat & 15) << 2;
    int ig = wi * 64 + rr;
    const float* src = (ig < 256) ? (Wx + (size_t)ig * 8192 + C0 + c4)
                                  : (Wh + (size_t)(ig - 256) * 8192 + C0 + c4);
    float4v v = *(const float4v*)src;
    float4v w;
#pragma unroll
    for (int e = 0; e < 4; ++e) w[e] = v[e] * 16.0f;
    *(float4v*)&tile[rr][c4] = w;
  }
  __syncthreads();
  int c = tid & 63, gq = tid >> 6;
  int C = C0 + c;
  int g = C >> 11, kk = (C >> 8) & 7, mm = C & 255;
  int p = ((mm >> 3) << 8) | ((g >> 1) << 7) | ((g & 1) << 6)
        | ((kk >> 1) << 4) | ((kk & 1) << 3) | (mm & 7);
  uint4v o;
  o[0] = pk4fp8(tile[gq * 8 + 0][c], tile[gq * 8 + 1][c], tile[gq * 8 + 2][c], tile[gq * 8 + 3][c]);
  o[1] = pk4fp8(tile[gq * 8 + 4][c], tile[gq * 8 + 5][c], tile[gq * 8 + 6][c], tile[gq * 8 + 7][c]);
  o[2] = pk4fp8(tile[32 + gq * 8 + 0][c], tile[32 + gq * 8 + 1][c], tile[32 + gq * 8 + 2][c], tile[32 + gq * 8 + 3][c]);
  o[3] = pk4fp8(tile[32 + gq * 8 + 4][c], tile[32 + gq * 8 + 5][c], tile[32 + gq * 8 + 6][c], tile[32 + gq * 8 + 7][c]);
  int cl = p & 255;   // q=cl>>6, wn=(cl>>4)&3, lane=cl&15
  int off = ((cl >> 6) << 12) + (((cl >> 4) & 3) << 10) + (gq << 8) + ((cl & 15) << 4);
  *(uint4v*)(Bt + (size_t)(p >> 8) * 131072 + wi * 16384 + off) = o;
}

// ---------------- G: fp8 128x256-tile GEMM, 3-slot rotation -----------------------
// 8 waves = 2M(wm) x 4N(wn). Per wave: 64 rows (wm*64 + j*16 + gl*4 + r),
// lane cols = 4 gate-quadrants q of one (kk,mm): kk = wn*2+(ml>>3), mml = ml&7.
// acc[q][j]: 16 float4v = 64 f32/lane.
__global__ __launch_bounds__(512, 4) void gates_kernel(
    const uint8_t* __restrict__ A,    // [rb 64][kt 8][8KB] fp8
    const uint8_t* __restrict__ Bt,   // [cb 32][kt 8][16KB] fp8
    const float* __restrict__ c0g,    // [8192][256]
    const float* __restrict__ bias,   // [8192]
    const float* __restrict__ zg,     // [8192][8]
    float* __restrict__ h_out, float* __restrict__ c_out) {
  __shared__ char smem[73728];  // 3 slots x 24KB (A 8KB + B 16KB per slot)

  const int tid = threadIdx.x;
  const int lane = tid & 63, ml = lane & 15, gl = lane >> 4;
  const int wid = tid >> 6, wm = wid >> 2, wn = wid & 3;

  // XCD-stripe: xcd owns rb {8x..8x+7}, cb outer / rb inner.
  const int xcd = blockIdx.x & 7;
  const int j_  = blockIdx.x >> 3;          // 0..255
  const int cb  = j_ >> 3;                  // 0..31
  const int rb  = (xcd << 3) | (j_ & 7);    // 0..63
  const int row0 = rb << 7;

  const uint8_t* Abp = A + (size_t)rb * 65536;
  const uint8_t* Bbp = Bt + (size_t)cb * 131072;

  // fragment LDS bases — quarter-wave-contiguous (conflict-free, R9-verified)
  const char* pa = smem + (wm << 12) + (gl << 8) + (ml << 4);           // + slot*24576 + j*1024
  const char* pb = smem + 8192 + (wn << 10) + (gl << 8) + (ml << 4);    // + slot*24576 + q*4096

  // stage kt-slot: A 8KB + B 16KB = 3 gll16/thread, fully linear
#define STGF(KTS) do { \
    const int sl_ = (KTS) % 3; \
    gll16(Abp + ((KTS) & 7) * 8192 + (tid << 4), \
          smem + sl_ * 24576 + (tid << 4)); \
    _Pragma("unroll") for (int s_ = 0; s_ < 2; ++s_) \
      gll16(Bbp + ((KTS) & 7) * 16384 + s_ * 8192 + (tid << 4), \
            smem + sl_ * 24576 + 8192 + s_ * 8192 + (tid << 4)); \
  } while (0)

#define RDAB(SL) { \
    _Pragma("unroll") for (int j = 0; j < 4; ++j) \
      af[j] = *(const llong2v*)(pa + (SL) * 24576 + j * 1024); \
    _Pragma("unroll") for (int q = 0; q < 4; ++q) \
      bf[q] = *(const llong2v*)(pb + (SL) * 24576 + q * 4096); }

#define MMALL() { _Pragma("unroll") for (int j = 0; j < 4; ++j) \
    _Pragma("unroll") for (int q = 0; q < 4; ++q) { \
      acc[q][j] = __builtin_amdgcn_mfma_f32_16x16x32_fp8_fp8(af[j][0], bf[q][0], acc[q][j], 0, 0, 0); \
      acc[q][j] = __builtin_amdgcn_mfma_f32_16x16x32_fp8_fp8(af[j][1], bf[q][1], acc[q][j], 0, 0, 0); } }

  float4v acc[4][4];   // [gate q][row frag j]
#pragma unroll
  for (int q = 0; q < 4; ++q)
#pragma unroll
    for (int j = 0; j < 4; ++j)
#pragma unroll
      for (int r = 0; r < 4; ++r) acc[q][j][r] = 0.0f;

  llong2v af[4], bf[4];

  // prologue: stage kt0,kt1 (6 loads); own s0 landed at vmcnt(3); barrier = all
  STGF(0); STGF(1);
  WAITVM(3);
  BARRIER;

#pragma unroll
  for (int kt = 0; kt < 8; ++kt) {
    if (kt <= 5) {
      STGF(kt + 2);                // slot (kt+2)%3 = (kt-1)%3: readers done pre-BARRIER_{kt-1}
      WAITVM(3);                   // leave only s(kt+2): s(kt+1) landed before BARRIER_kt
    } else if (kt == 6) {
      WAITVM(0);                   // drain s7 for kt=7's reads
    }
    RDAB(kt % 3);                  // 8 x ds_read_b128 (compiler emits counted lgkm waits)
    PRIO1; MMALL(); PRIO0;         // 32 MFMA — overlaps the in-flight stage
    BARRIER;                       // single barrier per kt
  }
#undef STGF
#undef RDAB
#undef MMALL

  // ---------------- fused LSTM epilogue (all slots free after BARRIER_7) ----------
  const int kkl = (wn << 1) | (ml >> 3);
  const int mml = ml & 7;
  {
    const int mmg = (cb << 3) + mml;
    const float bI = bias[0 * 2048 + kkl * 256 + mmg];
    const float bG = bias[1 * 2048 + kkl * 256 + mmg];
    const float bF = bias[2 * 2048 + kkl * 256 + mmg];
    const float bO = bias[3 * 2048 + kkl * 256 + mmg];
    const float s16 = 0.0625f;   // undo W*16 pre-scale

    float hpart[4][4], cpart[4][4];
#pragma unroll
    for (int j = 0; j < 4; ++j) {
      const int nb = row0 + (wm << 6) + (j << 4) + (gl << 2);
#pragma unroll
      for (int r = 0; r < 4; ++r) {
        const int nrow = nb + r;
        float I = fmaf(acc[0][j][r], s16, bI);
        float G = fmaf(acc[1][j][r], s16, bG);
        float F = fmaf(acc[2][j][r], s16, bF);
        float O = fmaf(acc[3][j][r], s16, bO);
        float c0v = c0g[(size_t)nrow * 256 + mmg];
        float ct = fmaf(sigm(F), c0v, sigm(I) * tanh_(G));
        float ht = sigm(O) * tanh_(ct);
        float zv = zg[(size_t)nrow * 8 + kkl];
        float h1 = zv * ht, c1 = zv * ct;
        h1 += __shfl_xor(h1, 8, 64);    // combine the wave's kk pair
        c1 += __shfl_xor(c1, 8, 64);
        hpart[j][r] = h1;
        cpart[j][r] = c1;
      }
    }

    // pbuf [wn 4][row 128][16] : cols 0..7 = h, 8..15 = c (32KB, reuses slots 0-1)
    float* pbuf = (float*)smem;
    const bool wr = ((ml & 8) == 0);
    if (wr) {
#pragma unroll
      for (int j = 0; j < 4; ++j)
#pragma unroll
        for (int r = 0; r < 4; ++r) {
          int rloc = (wm << 6) + (j << 4) + (gl << 2) + r;
          pbuf[(wn << 11) + (rloc << 4) + mml]     = hpart[j][r];
          pbuf[(wn << 11) + (rloc << 4) + 8 + mml] = cpart[j][r];
        }
    }
    WAITLGKM; BARRIER;
    // reduce over wn and store: 128 rows x 8 cols, h+c, 2 idx/thread
#pragma unroll
    for (int i = 0; i < 2; ++i) {
      int idx = (i << 9) + tid;          // 0..1023
      int rloc = idx >> 3, mm2 = idx & 7;
      float hv = pbuf[(rloc << 4) + mm2]
               + pbuf[2048 + (rloc << 4) + mm2]
               + pbuf[4096 + (rloc << 4) + mm2]
               + pbuf[6144 + (rloc << 4) + mm2];
      float cv = pbuf[(rloc << 4) + 8 + mm2]
               + pbuf[2048 + (rloc << 4) + 8 + mm2]
               + pbuf[4096 + (rloc << 4) + 8 + mm2]
               + pbuf[6144 + (rloc << 4) + 8 + mm2];
      h_out[(size_t)(row0 + rloc) * 256 + (cb << 3) + mm2] = hv;
      c_out[(size_t)(row0 + rloc) * 256 + (cb << 3) + mm2] = cv;
    }
  }
}

extern "C" void kernel_launch(void* const* d_in, const int* in_sizes, int n_in,
                              void* d_out, int out_size, void* d_ws, size_t ws_size,
                              hipStream_t stream) {
  const float* x   = (const float*)d_in[0];
  const float* h0  = (const float*)d_in[1];
  const float* c0  = (const float*)d_in[2];
  const float* u   = (const float*)d_in[3];
  const float* Wxz = (const float*)d_in[4];
  const float* Whz = (const float*)d_in[5];
  const float* Wx4 = (const float*)d_in[6];
  const float* Wh4 = (const float*)d_in[7];
  const float* bxz = (const float*)d_in[8];
  const float* b4  = (const float*)d_in[9];
  const void*  tau = d_in[10];

  float* out    = (float*)d_out;
  float* z_out  = out;                       // [8192][8]
  float* qz_out = out + 65536;               // [8192][8]
  float* h_out  = out + 131072;              // [8192][256]
  float* c_out  = out + 131072 + 2097152;    // [8192][256]

  uint8_t* A  = (uint8_t*)d_ws;              // 4MB fp8
  uint8_t* Bt = A + 4194304;                 // 4MB fp8

  prep_all<<<3072, 256, 0, stream>>>(x, h0, u, Wxz, Whz, bxz, tau,
                                     Wx4, Wh4, A, Bt, z_out, qz_out);
  gates_kernel<<<2048, 512, 0, stream>>>(A, Bt, c0, b4, z_out, h_out, c_out);
}